// Round 3
// baseline (706.249 us; speedup 1.0000x reference)
//
#include <hip/hip_runtime.h>
#include <stdint.h>

#define NB 32
#define SL 1024
#define HD 512
#define NS (NB * SL)   // 32768

typedef __attribute__((ext_vector_type(8))) short short8;   // 8 x bf16
typedef __attribute__((ext_vector_type(4))) short short4v;  // 4 x bf16
typedef __attribute__((ext_vector_type(4))) float f32x4;

__device__ __forceinline__ unsigned short f2bf(float f) {
    union { float f; uint32_t u; } c; c.f = f;
    uint32_t u = c.u;
    return (unsigned short)((u + 0x7FFFu + ((u >> 16) & 1u)) >> 16);
}

__device__ __forceinline__ void gl_lds16(const void* g, void* l) {
    __builtin_amdgcn_global_load_lds(
        (const __attribute__((address_space(1))) uint32_t*)g,
        (__attribute__((address_space(3))) uint32_t*)l, 16, 0, 0);
}

__device__ __forceinline__ f32x4 ntload4(const float* p) {
    return __builtin_nontemporal_load((const f32x4*)p);
}

__device__ __forceinline__ void cvt8(const float* src, unsigned short* dst, int j) {
    const float4* p = (const float4*)src + (size_t)j * 2;
    float4 a = p[0], b = p[1];
    short8 v;
    v[0] = (short)f2bf(a.x); v[1] = (short)f2bf(a.y);
    v[2] = (short)f2bf(a.z); v[3] = (short)f2bf(a.w);
    v[4] = (short)f2bf(b.x); v[5] = (short)f2bf(b.y);
    v[6] = (short)f2bf(b.z); v[7] = (short)f2bf(b.w);
    *((short8*)dst + j) = v;
}

// ---------------- fused convert: x + 3 weights + den zero (one launch) ----------------
__global__ void k_cvtall(const float* __restrict__ x,
                         const float* __restrict__ Wq, const float* __restrict__ Wk,
                         const float* __restrict__ Wv,
                         unsigned short* __restrict__ xb,
                         unsigned short* __restrict__ Wqk, unsigned short* __restrict__ Wvb,
                         float* __restrict__ den) {
    const int XC = NS * HD / 8;        // 2097152
    const int WC = HD * HD / 8;        // 32768
    int i = blockIdx.x * blockDim.x + threadIdx.x;   // grid = XC + 3*WC exactly
    if (i < XC) {
        cvt8(x, xb, i);
    } else {
        int j = i - XC;
        if (j < WC)            cvt8(Wq, Wqk, j);
        else if (j < 2 * WC)   cvt8(Wk, Wqk + HD * HD, j - WC);
        else                   cvt8(Wv, Wvb, j - 2 * WC);
    }
    if (i < NB) den[i] = 0.f;
}

// ---------------- bf16 GEMM tile body: C[M][N] = A[M][K] * B[N][K]^T + bias ----------------
// BIAS_M==0: bias by col with split at nsplit; BIAS_M==1: bias by row.
template<int BIAS_M>
__device__ __forceinline__
void gemm_tile(const unsigned short* __restrict__ A,
               const unsigned short* __restrict__ Bm,
               const float* __restrict__ bias,
               const float* __restrict__ bias2,
               int nsplit,
               unsigned short* __restrict__ C,
               int m0, int n0, int N, int K,
               unsigned short* As, unsigned short* Bs) {
    const int t = threadIdx.x;
    const int lane = t & 63, w = t >> 6;
    const int wr = w >> 1, wc = w & 1;
    const int g = lane >> 4, lr = lane & 15;

    f32x4 acc[4][4];
#pragma unroll
    for (int i = 0; i < 4; i++)
#pragma unroll
        for (int j = 0; j < 4; j++) acc[i][j] = (f32x4){0.f, 0.f, 0.f, 0.f};

    for (int kt = 0; kt < K; kt += 64) {
#pragma unroll
        for (int i = 0; i < 4; i++) {
            int u = i * 256 + t;
            int row = u >> 3, c = u & 7;
            int sc = c ^ (row & 7);
            gl_lds16(A + (size_t)(m0 + row) * K + kt + sc * 8,
                     (char*)As + (size_t)(i * 256 + w * 64) * 16);
        }
#pragma unroll
        for (int i = 0; i < 4; i++) {
            int u = i * 256 + t;
            int row = u >> 3, c = u & 7;
            int sc = c ^ (row & 7);
            gl_lds16(Bm + (size_t)(n0 + row) * K + kt + sc * 8,
                     (char*)Bs + (size_t)(i * 256 + w * 64) * 16);
        }
        __syncthreads();
#pragma unroll
        for (int ks = 0; ks < 2; ks++) {
            short8 af[4], bf[4];
#pragma unroll
            for (int mf = 0; mf < 4; mf++) {
                int row = wr * 64 + mf * 16 + lr;
                int ch = (ks * 4 + g) ^ (row & 7);
                af[mf] = *(const short8*)((const char*)As + row * 128 + ch * 16);
            }
#pragma unroll
            for (int nf = 0; nf < 4; nf++) {
                int row = wc * 64 + nf * 16 + lr;
                int ch = (ks * 4 + g) ^ (row & 7);
                bf[nf] = *(const short8*)((const char*)Bs + row * 128 + ch * 16);
            }
#pragma unroll
            for (int mf = 0; mf < 4; mf++)
#pragma unroll
                for (int nf = 0; nf < 4; nf++)
                    acc[mf][nf] = __builtin_amdgcn_mfma_f32_16x16x32_bf16(
                        af[mf], bf[nf], acc[mf][nf], 0, 0, 0);
        }
        __syncthreads();
    }
#pragma unroll
    for (int mf = 0; mf < 4; mf++) {
#pragma unroll
        for (int nf = 0; nf < 4; nf++) {
            int col = n0 + wc * 64 + nf * 16 + lr;
            int row0 = m0 + wr * 64 + mf * 16 + g * 4;
            float cb = 0.f;
            if (!BIAS_M) cb = (col < nsplit) ? bias[col] : bias2[col - nsplit];
#pragma unroll
            for (int r = 0; r < 4; r++) {
                float v = acc[mf][nf][r] + (BIAS_M ? bias[row0 + r] : cb);
                C[(size_t)(row0 + r) * N + col] = f2bf(v);
            }
        }
    }
}

// Fused projections: blocks [0,2048) -> [Q|K] = xb*Wqk^T; blocks [2048,3072) -> Vt = Wvb*xb^T.
__global__ __launch_bounds__(256, 4)
void k_gemm2(const unsigned short* __restrict__ xb,
             const unsigned short* __restrict__ Wqk,
             const unsigned short* __restrict__ Wvb,
             const float* __restrict__ bq, const float* __restrict__ bk,
             const float* __restrict__ bv,
             unsigned short* __restrict__ QKm,
             unsigned short* __restrict__ Vt) {
    __shared__ unsigned short As[128 * 64];
    __shared__ unsigned short Bs[128 * 64];
    int bid = blockIdx.x;
    if (bid < 2048) {
        // XCD-chunked: each XCD gets 32 contiguous row-panels x 8 col-tiles
        int nid = (bid & 7) * 256 + (bid >> 3);
        int bx = nid & 7, by = nid >> 3;
        gemm_tile<0>(xb, Wqk, bq, bk, HD, QKm,
                     by * 128, bx * 128, 1024, HD, As, Bs);
    } else {
        int b2 = bid - 2048;
        int nid = (b2 & 7) * 128 + (b2 >> 3);
        int x = nid >> 2, y = nid & 3;   // x: 256 col-tiles of NS, y: 4 row-tiles of HD
        gemm_tile<1>(Wvb, xb, bv, bv, 1 << 30, Vt,
                     y * 128, x * 128, NS, HD, As, Bs);
    }
}

// ---------------- fused attention (no-max softmax, swapped QK^T) ----------------
// Block: 1024 threads = 16 waves; QBLK=32 q-rows; K in 2 tiles of 512.
// Wave w: k-slice [w*32,+32) for QK^T; h-slice [w*32,+32) for PV.
// LDS ~70KB -> 2 blocks/CU -> 32 waves/CU.
__global__ __launch_bounds__(1024, 8)
void k_flash(const unsigned short* __restrict__ QK,  // [NS][1024]: 0..511 Q, 512..1023 K
             const unsigned short* __restrict__ Vt,  // [HD][NS]
             const float* __restrict__ mask,         // [NB][SL][SL]
             float* __restrict__ out,                // [NB][SL][HD]
             float* __restrict__ denom) {            // [NB]
    __shared__ unsigned short Qs[32 * 512];   // 32KB, 16B-chunk swizzled
    __shared__ unsigned short Ps[32 * 512];   // 32KB
    __shared__ float wredL[16 * 32];
    __shared__ float wredA[16 * 32];
    __shared__ float tredL[32];
    __shared__ float tredA[32];

    const int t = threadIdx.x;
    const int lane = t & 63, w = t >> 6;
    const int g = lane >> 4, lr = lane & 15;
    // XCD swizzle: 1024 blocks -> each XCD owns 4 whole batches (batch-major)
    const int bid = blockIdx.x;
    const int nid = (bid & 7) * 128 + (bid >> 3);
    const int b = nid >> 5, qt = nid & 31;
    const int q0 = qt * 32;

    // stage Q tile 32x512 bf16 (chunk-swizzled), 2 rounds of 16KB
    const unsigned short* Qg = QK + (size_t)(b * SL + q0) * 1024;
#pragma unroll
    for (int i = 0; i < 2; i++) {
        int u = i * 1024 + t;
        int row = u >> 6, c = u & 63;
        int sc = c ^ (row & 7);
        gl_lds16(Qg + (size_t)row * 1024 + sc * 8,
                 (char*)Qs + (size_t)(i * 1024 + w * 64) * 16);
    }

    f32x4 O[2][2];
    float lsum[2], asum[2];
#pragma unroll
    for (int qf = 0; qf < 2; qf++) {
        lsum[qf] = 0.f; asum[qf] = 0.f;
        O[qf][0] = (f32x4){0.f, 0.f, 0.f, 0.f};
        O[qf][1] = (f32x4){0.f, 0.f, 0.f, 0.f};
    }
    __syncthreads();   // Q staged

    const float iscale = 0.04419417382415922f;  // 1/sqrt(512)

    for (int kt = 0; kt < 2; kt++) {
        // ---- prefetch mask (independent of QK^T; hides HBM latency under MFMA) ----
        const float* mrow = mask + ((size_t)(b * SL + q0)) * SL + kt * 512 + w * 32;
        f32x4 mv[2][2];
#pragma unroll
        for (int qf = 0; qf < 2; qf++)
#pragma unroll
            for (int kf = 0; kf < 2; kf++)
                mv[qf][kf] = ntload4(mrow + (size_t)(qf * 16 + lr) * SL + kf * 16 + g * 4);

        // ---- QK^T (swapped): per wave P^T[k 32][q 32] ----
        f32x4 P[2][2];   // [kf][qf]
#pragma unroll
        for (int kf = 0; kf < 2; kf++)
#pragma unroll
            for (int qf = 0; qf < 2; qf++) P[kf][qf] = (f32x4){0.f, 0.f, 0.f, 0.f};

        const unsigned short* Kg = QK + 512 + (size_t)(b * SL + kt * 512 + w * 32) * 1024;
#pragma unroll 4
        for (int h = 0; h < HD; h += 32) {
            short8 ka[2], qb[2];
#pragma unroll
            for (int kf = 0; kf < 2; kf++)
                ka[kf] = *(const short8*)(Kg + (size_t)(kf * 16 + lr) * 1024 + h + g * 8);
#pragma unroll
            for (int qf = 0; qf < 2; qf++) {
                int q = qf * 16 + lr;
                int sc = ((h >> 3) + g) ^ (q & 7);
                qb[qf] = *(const short8*)((const char*)Qs + q * 1024 + sc * 16);
            }
#pragma unroll
            for (int kf = 0; kf < 2; kf++)
#pragma unroll
                for (int qf = 0; qf < 2; qf++)
                    P[kf][qf] = __builtin_amdgcn_mfma_f32_16x16x32_bf16(
                        ka[kf], qb[qf], P[kf][qf], 0, 0, 0);
        }

        if (kt) __syncthreads();   // all waves done reading Ps (prev tile PV)

        // ---- exp, A=e*mk, Ps write, partial sums ----
#pragma unroll
        for (int qf = 0; qf < 2; qf++) {
            int q = qf * 16 + lr;
#pragma unroll
            for (int kf = 0; kf < 2; kf++) {
                f32x4 e;
#pragma unroll
                for (int r = 0; r < 4; r++) e[r] = __expf(P[kf][qf][r] * iscale);
                lsum[qf] += e[0] + e[1] + e[2] + e[3];
                f32x4 a = e * mv[qf][kf];
                asum[qf] += a[0] + a[1] + a[2] + a[3];
                short4v pk;
                pk[0] = (short)f2bf(a[0]); pk[1] = (short)f2bf(a[1]);
                pk[2] = (short)f2bf(a[2]); pk[3] = (short)f2bf(a[3]);
                int chunk = w * 4 + kf * 2 + (g >> 1);
                int sc = chunk ^ (q & 7);
                *(short4v*)((char*)Ps + q * 1024 + sc * 16 + (g & 1) * 8) = pk;
            }
        }
        __syncthreads();   // Ps ready

        // ---- PV: O[q 32][h 32-per-wave] += P * Vt ----
        const unsigned short* Vg = Vt + (size_t)(w * 32) * NS + (size_t)b * SL + kt * 512;
#pragma unroll 4
        for (int ks = 0; ks < 512; ks += 32) {
            short8 pa[2], vb[2];
#pragma unroll
            for (int qf = 0; qf < 2; qf++) {
                int q = qf * 16 + lr;
                int sc = ((ks >> 3) + g) ^ (q & 7);
                pa[qf] = *(const short8*)((const char*)Ps + q * 1024 + sc * 16);
            }
#pragma unroll
            for (int nh = 0; nh < 2; nh++)
                vb[nh] = *(const short8*)(Vg + (size_t)(nh * 16 + lr) * NS + ks + g * 8);
#pragma unroll
            for (int qf = 0; qf < 2; qf++)
#pragma unroll
                for (int nh = 0; nh < 2; nh++)
                    O[qf][nh] = __builtin_amdgcn_mfma_f32_16x16x32_bf16(
                        pa[qf], vb[nh], O[qf][nh], 0, 0, 0);
        }
    }

    // ---- deferred row-sum reduction (once) ----
#pragma unroll
    for (int qf = 0; qf < 2; qf++) {
        float L = lsum[qf], A = asum[qf];
        L += __shfl_xor(L, 16); L += __shfl_xor(L, 32);
        A += __shfl_xor(A, 16); A += __shfl_xor(A, 32);
        if (g == 0) {
            wredL[w * 32 + qf * 16 + lr] = L;
            wredA[w * 32 + qf * 16 + lr] = A;
        }
    }
    __syncthreads();
    if (t < 32) {
        float L = 0.f, A = 0.f;
#pragma unroll
        for (int ww = 0; ww < 16; ww++) { L += wredL[ww * 32 + t]; A += wredA[ww * 32 + t]; }
        tredL[t] = L; tredA[t] = A;
    }
    __syncthreads();

    // ---- epilogue: out = O / l ----
#pragma unroll
    for (int qf = 0; qf < 2; qf++) {
        f32x4 Lv = *(const f32x4*)&tredL[qf * 16 + g * 4];
#pragma unroll
        for (int r = 0; r < 4; r++) {
            float invl = 1.0f / Lv[r];
            size_t rowoff = (size_t)(b * SL + q0 + qf * 16 + g * 4 + r) * HD;
#pragma unroll
            for (int nh = 0; nh < 2; nh++)
                out[rowoff + w * 32 + nh * 16 + lr] = O[qf][nh][r] * invl;
        }
    }
    if (t < 32) {
        float d = tredA[t] / tredL[t];
        d += __shfl_xor(d, 1); d += __shfl_xor(d, 2); d += __shfl_xor(d, 4);
        d += __shfl_xor(d, 8); d += __shfl_xor(d, 16);
        if (t == 0) atomicAdd(&denom[b], d);
    }
}

// Normalize; block->batch map matches k_flash's XCD swizzle so reads hit same-XCD L2.
__global__ void k_norm(float* __restrict__ out, const float* __restrict__ denom) {
    const int bid = blockIdx.x;                     // 1024 blocks
    const int nid = (bid & 7) * 128 + (bid >> 3);
    const int b = nid >> 5;
    const float inv = 1.0f / denom[b];
    float4* p = (float4*)out + (size_t)nid * 4096;
#pragma unroll 4
    for (int j = threadIdx.x; j < 4096; j += 256) {
        float4 v = p[j];
        v.x *= inv; v.y *= inv; v.z *= inv; v.w *= inv;
        p[j] = v;
    }
}

extern "C" void kernel_launch(void* const* d_in, const int* in_sizes, int n_in,
                              void* d_out, int out_size, void* d_ws, size_t ws_size,
                              hipStream_t stream) {
    const float* x    = (const float*)d_in[0];
    const float* mask = (const float*)d_in[1];
    const float* Wq   = (const float*)d_in[2];
    const float* bq   = (const float*)d_in[3];
    const float* Wk   = (const float*)d_in[4];
    const float* bk   = (const float*)d_in[5];
    const float* Wv   = (const float*)d_in[6];
    const float* bv   = (const float*)d_in[7];
    float* out = (float*)d_out;

    const size_t SZ_X = (size_t)NS * HD * 2;   // 33.55 MB
    const size_t SZ_W = (size_t)HD * HD * 2;

    size_t off = 0;
    char* base = (char*)d_ws;
    unsigned short* xb  = (unsigned short*)(base + off); off += SZ_X;
    unsigned short* Vt  = (unsigned short*)(base + off); off += SZ_X;
    unsigned short* QKm = (unsigned short*)(base + off); off += 2 * SZ_X;  // [NS][1024]
    unsigned short* Wqk = (unsigned short*)(base + off); off += 2 * SZ_W;  // [1024][512]
    unsigned short* Wvb = (unsigned short*)(base + off); off += SZ_W;
    float* den = (float*)(base + off); off += 256;

    // converts: exact grid (XC + 3*WC)/256 = 8576
    hipLaunchKernelGGL(k_cvtall, dim3(8576), dim3(256), 0, stream,
                       x, Wq, Wk, Wv, xb, Wqk, Wvb, den);

    // fused projections: [Q|K] (2048 tiles) + Vt (1024 tiles)
    hipLaunchKernelGGL(k_gemm2, dim3(3072), dim3(256), 0, stream,
                       xb, Wqk, Wvb, bq, bk, bv, QKm, Vt);

    hipLaunchKernelGGL(k_flash, dim3(1024), dim3(1024), 0, stream,
                       QKm, Vt, mask, out, den);
    hipLaunchKernelGGL(k_norm, dim3(1024), dim3(256), 0, stream, out, den);
}